// Round 3
// baseline (387.133 us; speedup 1.0000x reference)
//
#include <hip/hip_runtime.h>

// WTConv2d fused (see R0 derivation):
// out = (conv3x3(x, base_w)+base_b)*base_scale
//     + wavelet_scale * U( U(conv3x3(t1, ws1)) + conv3x3(t0, ws0) )
// t0 = D(x), t1 = D(t0); D = stride-2 2x2 corr, +-0.25 signs by c>>6;
// U = 2x upsample, +-0.5 signs by c>>6; ws1 = w_ll+w_lh1+w_hl1+w_hh1,
// ws0 = w_lh0+w_hl0+w_hh0.
//
// R5: wave-decoupled. R2/R3/R4 all ~130us with every pipe <=40% => the
// block-wide barrier convoy is the bottleneck, not any pipe. Each WAVE now
// owns a 56x32 tile end-to-end with wave-private LDS pyramid buffers;
// cross-lane handoff needs only s_waitcnt lgkmcnt(0) (lockstep wave), so
// there are ZERO __syncthreads. Base conv computed from registers (10-row
// float4 slab per lane, neighbors via intra-wave __shfl), so xs and its
// structural bank conflicts are gone. Uniform weights -> SGPR via
// readfirstlane. LDS 23.2KB -> 6 blocks/CU = 24 independent waves.

#define HH 224
#define WW 224
#define CC 256
#define BB 4

#define WAVE_SYNC asm volatile("s_waitcnt lgkmcnt(0)" ::: "memory")

__device__ __forceinline__ float rfl(float v) {
    return __uint_as_float(__builtin_amdgcn_readfirstlane(__float_as_uint(v)));
}

__global__ __launch_bounds__(256, 6) void wtconv_fused(
    const float* __restrict__ x,
    const float* __restrict__ base_w,
    const float* __restrict__ base_b,
    const float* __restrict__ base_scale,
    const float* __restrict__ wavelet_scale,
    const float* __restrict__ w_ll,
    const float* __restrict__ w_lh0,
    const float* __restrict__ w_hl0,
    const float* __restrict__ w_hh0,
    const float* __restrict__ w_lh1,
    const float* __restrict__ w_hl1,
    const float* __restrict__ w_hh1,
    float* __restrict__ out)
{
    // per-wave pyramid buffers (wave-private slices)
    __shared__ float t0s[4][20][34];  // t0 rows A0-2..A0+17, cols B0-2..B0+29
    __shared__ float t1s[4][10][17];  // t1 rows A1-1..A1+8, cols B1-1..B1+15
    __shared__ float a1s[4][8][15];   // a1 rows A1..A1+7,  cols B1..B1+13
    __shared__ float a0s[4][16][30];  // a0 rows A0..A0+15, cols B0..B0+27
    // total 10880+2720+1920+7680 = 23200 B -> 6 blocks/CU, 24 indep waves

    const int tid   = threadIdx.x;
    const int wid   = tid >> 6;      // wave id = column tile
    const int lane  = tid & 63;
    const int k     = lane & 15;     // col group (float4)
    const int rp    = lane >> 4;     // row group (10 rows each)
    const int strip = blockIdx.x;    // 0..6  (rows of tiles)
    const int c     = blockIdx.y;
    const int b     = blockIdx.z;

    const int R0 = 32 * strip;       // tile origin
    const int C0 = 56 * wid;

    const int f = c >> 6;                   // faithful quirk: filter idx = c//64
    const float sR = (f & 1) ? -1.f : 1.f;
    const float sC = (f & 2) ? -1.f : 1.f;

    float ws1[9], ws0[9], bw[9];
#pragma unroll
    for (int j = 0; j < 9; ++j) {
        const int o = c * 9 + j;
        ws1[j] = rfl(w_ll[o] + w_lh1[o] + w_hl1[o] + w_hh1[o]);
        ws0[j] = rfl(w_lh0[o] + w_hl0[o] + w_hh0[o]);
        bw[j]  = rfl(base_w[o]);
    }
    const float bb  = rfl(base_b[c]);
    const float bsc = rfl(base_scale[c]);
    const float wsc = rfl(wavelet_scale[c]);

    const float* xp = x   + (size_t)(b * CC + c) * (HH * WW);
    float*       op = out + (size_t)(b * CC + c) * (HH * WW);

    // ---- load: lane (k,rp) holds x rows R0-4+10rp .. +9, cols C0-4+4k .. +3
    float4 X[10];
    {
        const int gc = C0 - 4 + 4 * k;
        const bool cok = (gc >= 0) & (gc <= WW - 4);
#pragma unroll
        for (int i = 0; i < 10; ++i) {
            const int gr = R0 - 4 + 10 * rp + i;
            float4 v = make_float4(0.f, 0.f, 0.f, 0.f);
            if (cok & (gr >= 0) & (gr < HH))
                v = *(const float4*)(xp + (size_t)gr * WW + gc);
            X[i] = v;
        }
    }

    // ---- t0 = D(x): lane writes t0 rows 5rp..5rp+4, cols 2k,2k+1 ----
#pragma unroll
    for (int a = 0; a < 5; ++a) {
        const float4 v0 = X[2 * a];
        const float4 v1 = X[2 * a + 1];
        const float e = (v0.x + sC * v0.y) + sR * (v1.x + sC * v1.y);
        const float o = (v0.z + sC * v0.w) + sR * (v1.z + sC * v1.w);
        *(float2*)&t0s[wid][5 * rp + a][2 * k] = make_float2(0.25f * e, 0.25f * o);
    }
    WAVE_SYNC;

    // ---- t1 = D(t0): 10x16 = 160 elems, lane-flat ----
#pragma unroll
    for (int j = 0; j < 3; ++j) {
        const int e = lane + 64 * j;
        if (e < 160) {
            const int m = e >> 4;
            const int n = e & 15;
            const float2 p = *(const float2*)&t0s[wid][2 * m][2 * n];
            const float2 q = *(const float2*)&t0s[wid][2 * m + 1][2 * n];
            t1s[wid][m][n] = 0.25f * ((p.x + sC * p.y) + sR * (q.x + sC * q.y));
        }
    }
    WAVE_SYNC;

    // ---- a1 = conv3x3(t1, ws1): 8x14 ----
    const int col  = lane & 15;
    const int row4 = lane >> 4;
    if (col < 14) {
#pragma unroll
        for (int j = 0; j < 2; ++j) {
            const int g = row4 + 4 * j;
            float acc = 0.f;
#pragma unroll
            for (int u = 0; u < 3; ++u) {
                acc += t1s[wid][g + u][col]     * ws1[3 * u]
                     + t1s[wid][g + u][col + 1] * ws1[3 * u + 1]
                     + t1s[wid][g + u][col + 2] * ws1[3 * u + 2];
            }
            a1s[wid][g][col] = acc;
        }
    }
    WAVE_SYNC;

    // ---- a0 = U(a1) + conv3x3(t0, ws0): 16 x 28 (14 col pairs) ----
    if (col < 14) {
#pragma unroll
        for (int j = 0; j < 4; ++j) {
            const int r = row4 + 4 * j;          // 0..15
            float s0 = 0.f, s1 = 0.f;
#pragma unroll
            for (int u = 0; u < 3; ++u) {
                const float2 A  = *(const float2*)&t0s[wid][r + 1 + u][2 * col];
                const float2 Bq = *(const float2*)&t0s[wid][r + 1 + u][2 * col + 2];
                const float2 Cq = *(const float2*)&t0s[wid][r + 1 + u][2 * col + 4];
                const float w0 = ws0[3 * u], w1 = ws0[3 * u + 1], w2 = ws0[3 * u + 2];
                s0 += A.y  * w0 + Bq.x * w1 + Bq.y * w2;
                s1 += Bq.x * w0 + Bq.y * w1 + Cq.x * w2;
            }
            const float av = a1s[wid][r >> 1][col];
            const float e = 0.5f * ((r & 1) ? sR : 1.f);
            const float o = e * sC;
            *(float2*)&a0s[wid][r][2 * col] = make_float2(s0 + e * av, s1 + o * av);
        }
    }
    WAVE_SYNC;

    // ---- epilogue: base conv from registers + wsc*U(a0), store ----
    // lane covers out rows o = 10rp-5+jj (jj=0..9), out cols 4(k-1)..+3
    const int kk  = k - 1;
    const bool kok = (k >= 1) & (k <= 14);
    const int kc  = kok ? kk : 0;
    const float we = wsc * 0.5f;

    // x̂[-2], x̂[-1]: rows 10rp-2, 10rp-1 from lane-16
    float4 w0v, w1v;
    {
        const float4 t8 = X[8], t9 = X[9];
        w0v.x = __shfl(t8.x, lane - 16); w0v.y = __shfl(t8.y, lane - 16);
        w0v.z = __shfl(t8.z, lane - 16); w0v.w = __shfl(t8.w, lane - 16);
        w1v.x = __shfl(t9.x, lane - 16); w1v.y = __shfl(t9.y, lane - 16);
        w1v.z = __shfl(t9.z, lane - 16); w1v.w = __shfl(t9.w, lane - 16);
    }
    float l0 = __shfl(w0v.w, lane - 1), r0 = __shfl(w0v.x, lane + 1);
    float l1 = __shfl(w1v.w, lane - 1), r1 = __shfl(w1v.x, lane + 1);

#pragma unroll
    for (int jj = 0; jj < 10; ++jj) {
        const float4 w2v = X[jj];
        const float l2 = __shfl(w2v.w, lane - 1);
        const float r2 = __shfl(w2v.x, lane + 1);
        const int o = 10 * rp - 5 + jj;

        const float acc0 = l0    * bw[0] + w0v.x * bw[1] + w0v.y * bw[2]
                         + l1    * bw[3] + w1v.x * bw[4] + w1v.y * bw[5]
                         + l2    * bw[6] + w2v.x * bw[7] + w2v.y * bw[8];
        const float acc1 = w0v.x * bw[0] + w0v.y * bw[1] + w0v.z * bw[2]
                         + w1v.x * bw[3] + w1v.y * bw[4] + w1v.z * bw[5]
                         + w2v.x * bw[6] + w2v.y * bw[7] + w2v.z * bw[8];
        const float acc2 = w0v.y * bw[0] + w0v.z * bw[1] + w0v.w * bw[2]
                         + w1v.y * bw[3] + w1v.z * bw[4] + w1v.w * bw[5]
                         + w2v.y * bw[6] + w2v.z * bw[7] + w2v.w * bw[8];
        const float acc3 = w0v.z * bw[0] + w0v.w * bw[1] + r0    * bw[2]
                         + w1v.z * bw[3] + w1v.w * bw[4] + r1    * bw[5]
                         + w2v.z * bw[6] + w2v.w * bw[7] + r2    * bw[8];

        const int oc = o < 0 ? 0 : (o > 31 ? 31 : o);
        const float2 ap = *(const float2*)&a0s[wid][oc >> 1][2 * kc];
        const float ww0 = (o & 1) ? we * sR : we;
        const float ww1 = ww0 * sC;

        if (kok & (o >= 0) & (o <= 31)) {
            float4 ov;
            ov.x = (acc0 + bb) * bsc + ww0 * ap.x;
            ov.y = (acc1 + bb) * bsc + ww1 * ap.x;
            ov.z = (acc2 + bb) * bsc + ww0 * ap.y;
            ov.w = (acc3 + bb) * bsc + ww1 * ap.y;
            *(float4*)(op + (size_t)(R0 + o) * WW + C0 + 4 * kk) = ov;
        }
        w0v = w1v; l0 = l1; r0 = r1;
        w1v = w2v; l1 = l2; r1 = r2;
    }
}

extern "C" void kernel_launch(void* const* d_in, const int* in_sizes, int n_in,
                              void* d_out, int out_size, void* d_ws, size_t ws_size,
                              hipStream_t stream) {
    const float* x             = (const float*)d_in[0];
    const float* base_w        = (const float*)d_in[1];
    const float* base_b        = (const float*)d_in[2];
    const float* base_scale    = (const float*)d_in[3];
    const float* wavelet_scale = (const float*)d_in[4];
    const float* w_ll          = (const float*)d_in[5];
    const float* w_lh0         = (const float*)d_in[6];
    const float* w_hl0         = (const float*)d_in[7];
    const float* w_hh0         = (const float*)d_in[8];
    const float* w_lh1         = (const float*)d_in[9];
    const float* w_hl1         = (const float*)d_in[10];
    const float* w_hh1         = (const float*)d_in[11];
    float* out                 = (float*)d_out;

    dim3 grid(7, CC, BB);   // strips x channels x batch; wave = col tile
    dim3 block(256);
    hipLaunchKernelGGL(wtconv_fused, grid, block, 0, stream,
                       x, base_w, base_b, base_scale, wavelet_scale,
                       w_ll, w_lh0, w_hl0, w_hh0, w_lh1, w_hl1, w_hh1, out);
}